// Round 6
// baseline (410.130 us; speedup 1.0000x reference)
//
#include <hip/hip_runtime.h>

typedef unsigned int uint;
typedef unsigned short ushort;
typedef __attribute__((ext_vector_type(8))) short bf16x8;
typedef __attribute__((ext_vector_type(4))) float f32x4;

#define NN 100000
#define NE 800000
#define D_IN 256
#define D_HID 128
#define D_OUT 64

// RNE fp32->bf16
__device__ __forceinline__ ushort f2bf(float f) {
    uint u = __float_as_uint(f);
    return (ushort)((u + 0x7fffu + ((u >> 16) & 1u)) >> 16);
}
__device__ __forceinline__ float bflo(uint u) { return __uint_as_float(u << 16); }
__device__ __forceinline__ float bfhi(uint u) { return __uint_as_float(u & 0xffff0000u); }
__device__ __forceinline__ uint pack2(float lo, float hi) {
    return (uint)f2bf(lo) | ((uint)f2bf(hi) << 16);
}
__device__ __forceinline__ bf16x8 pack8(float4 a, float4 b) {
    bf16x8 r;
    r[0] = (short)f2bf(a.x); r[1] = (short)f2bf(a.y); r[2] = (short)f2bf(a.z); r[3] = (short)f2bf(a.w);
    r[4] = (short)f2bf(b.x); r[5] = (short)f2bf(b.y); r[6] = (short)f2bf(b.z); r[7] = (short)f2bf(b.w);
    return r;
}

// ---------------- degree count ----------------
__global__ __launch_bounds__(256) void k_count(const int* __restrict__ dst, int* __restrict__ count, int e) {
    int i = blockIdx.x * 256 + threadIdx.x;
    if (i < e) {
        unsigned d = (unsigned)dst[i];
        if (d < NN) atomicAdd(&count[d], 1);
    }
}

// ---------------- scan stage 1: per-1024-block inclusive scan + block sums ----------------
#define SCAN_B 1024
__global__ __launch_bounds__(SCAN_B) void k_scan1(const int* __restrict__ count, int* __restrict__ incl,
                                                  int* __restrict__ blocksum, int n) {
    __shared__ int tmp[SCAN_B];
    int t = threadIdx.x;
    int gid = blockIdx.x * SCAN_B + t;
    int v = (gid < n) ? count[gid] : 0;
    tmp[t] = v;
    __syncthreads();
    for (int off = 1; off < SCAN_B; off <<= 1) {
        int u = (t >= off) ? tmp[t - off] : 0;
        __syncthreads();
        tmp[t] += u;
        __syncthreads();
    }
    if (gid < n) incl[gid] = tmp[t];
    if (t == SCAN_B - 1) blocksum[blockIdx.x] = tmp[t];
}

// ---------------- scan stage 2 (merged): finalize offsets/cursor/dinv ----------------
__global__ __launch_bounds__(256) void k_scan3(const int* __restrict__ incl, const int* __restrict__ count,
                                               const int* __restrict__ blocksum, int nb, int* __restrict__ offsets,
                                               int* __restrict__ cursor, float* __restrict__ dinv, int n) {
    __shared__ int bs[128];
    int t = threadIdx.x;
    if (t < 128) bs[t] = (t < nb) ? blocksum[t] : 0;
    __syncthreads();
    int i = blockIdx.x * 256 + t;
    if (i < n) {
        int b = i >> 10;
        int off = 0;
        for (int j = 0; j < b; j++) off += bs[j];
        int inc = incl[i] + off;
        int exc = inc - count[i];
        offsets[i] = exc;
        cursor[i] = exc;
        dinv[i] = rsqrtf((float)(count[i] + 1));  // +1 self-loop
        if (i == n - 1) offsets[n] = inc;
    }
}

// ---------------- scatter edges into CSC order ----------------
__global__ __launch_bounds__(256) void k_scatter(const int* __restrict__ edges, int* __restrict__ cursor,
                                                 int* __restrict__ srcs, int e) {
    int i = blockIdx.x * 256 + threadIdx.x;
    if (i < e) {
        unsigned s = (unsigned)edges[i];
        unsigned d = (unsigned)edges[e + i];
        if (s < NN && d < NN) {
            int pos = atomicAdd(&cursor[d], 1);
            srcs[pos] = (int)s;
        }
    }
}

// ---------------- both weights: W[K][N] fp32 -> WT[N][K] bf16 ----------------
__global__ __launch_bounds__(256) void k_castW(const float* __restrict__ W1, const float* __restrict__ W2,
                                               ushort* __restrict__ w1t, ushort* __restrict__ w2t) {
    int t = blockIdx.x * 256 + threadIdx.x;
    if (t < D_IN * D_HID) {
        int n = t / D_IN, k = t % D_IN;
        w1t[t] = f2bf(W1[(size_t)k * D_HID + n]);
    } else {
        int u = t - D_IN * D_HID;
        if (u < D_HID * D_OUT) {
            int n = u / D_HID, k = u % D_HID;
            w2t[u] = f2bf(W2[(size_t)k * D_OUT + n]);
        }
    }
}

// ---------------- MFMA GEMM, 16 rows/wave, all A-loads issued up front (max MLP) ----------------
// C[M,N] = (A[M,K] @ B[K,N]) * dinv[row], bf16 out. BT = B^T [N][K] bf16.
template <int K_DIM, int N_DIM, bool AF32>
__global__ __launch_bounds__(256) void k_gemm16(const void* __restrict__ Av, const ushort* __restrict__ BT,
                                                const float* __restrict__ dinv, ushort* __restrict__ C, int M) {
    constexpr int NF = N_DIM / 16;
    constexpr int KK = K_DIM / 32;
    const int tid = threadIdx.x;
    const int w = tid >> 6, lane = tid & 63;
    const int l15 = lane & 15, g = lane >> 4;  // g in 0..3
    const int row0 = blockIdx.x * 64 + w * 16;
    const int row = min(row0 + l15, M - 1);

    bf16x8 a[KK];
    if constexpr (AF32) {
        const float* A = (const float*)Av;
        float4 ar[2 * KK];  // 16 independent 16B loads, all in flight before any use
#pragma unroll
        for (int kk = 0; kk < KK; kk++) {
            const float4* p = (const float4*)(A + (size_t)row * K_DIM + g * 8 + kk * 32);
            ar[2 * kk] = p[0];
            ar[2 * kk + 1] = p[1];
        }
#pragma unroll
        for (int kk = 0; kk < KK; kk++) a[kk] = pack8(ar[2 * kk], ar[2 * kk + 1]);
    } else {
        const ushort* A = (const ushort*)Av;
#pragma unroll
        for (int kk = 0; kk < KK; kk++)
            a[kk] = *reinterpret_cast<const bf16x8*>(A + (size_t)row * K_DIM + g * 8 + kk * 32);
    }

    f32x4 acc[NF];
#pragma unroll
    for (int nf = 0; nf < NF; nf++) acc[nf] = (f32x4){0.f, 0.f, 0.f, 0.f};

    const ushort* pb = BT + (size_t)l15 * K_DIM + g * 8;
#pragma unroll
    for (int kk = 0; kk < KK; kk++) {
#pragma unroll
        for (int nf = 0; nf < NF; nf++) {
            bf16x8 b = *reinterpret_cast<const bf16x8*>(pb + (size_t)nf * 16 * K_DIM + kk * 32);
            acc[nf] = __builtin_amdgcn_mfma_f32_16x16x32_bf16(a[kk], b, acc[nf], 0, 0, 0);
        }
    }

    // D layout: row_in_tile = g*4 + r, col = l15  [learn_hip m89/m91]
#pragma unroll
    for (int r = 0; r < 4; r++) {
        int rr = row0 + g * 4 + r;
        if (rr < M) {
            float dv = dinv[rr];
#pragma unroll
            for (int nf = 0; nf < NF; nf++)
                C[(size_t)rr * N_DIM + nf * 16 + l15] = f2bf(acc[nf][r] * dv);
        }
    }
}

// ---------------- pull aggregation, F=128 bf16 rows (256B), 16B/lane, 4 rows/wave-load ----------------
// h[i] = relu( dinv[i]*( hws[i] + sum_{e:dst=i} hws[src] ) + bias )
__global__ __launch_bounds__(256) void k_agg128(const ushort* __restrict__ hws, const int* __restrict__ srcs,
                                                const int* __restrict__ offs, const float* __restrict__ dinv,
                                                const float* __restrict__ bias, ushort* __restrict__ outb, int n) {
    const int wv = threadIdx.x >> 6, lane = threadIdx.x & 63;
    const int node = blockIdx.x * 4 + wv;
    if (node >= n) return;
    const int g = lane >> 4, l15 = lane & 15;
    const int beg = offs[node];
    const int T = offs[node + 1] - beg + 1;  // items: 0 = self, t>=1 -> srcs[beg+t-1]
    const uint4* base = (const uint4*)hws;   // row = 16 uint4
    float acc[8] = {};
    int t = g;
    for (; t + 4 < T; t += 8) {
        int s0 = (t == 0) ? node : srcs[beg + t - 1];
        int s1 = srcs[beg + t + 3];
        uint4 va = base[(size_t)s0 * 16 + l15];
        uint4 vb = base[(size_t)s1 * 16 + l15];
        acc[0] += bflo(va.x) + bflo(vb.x); acc[1] += bfhi(va.x) + bfhi(vb.x);
        acc[2] += bflo(va.y) + bflo(vb.y); acc[3] += bfhi(va.y) + bfhi(vb.y);
        acc[4] += bflo(va.z) + bflo(vb.z); acc[5] += bfhi(va.z) + bfhi(vb.z);
        acc[6] += bflo(va.w) + bflo(vb.w); acc[7] += bfhi(va.w) + bfhi(vb.w);
    }
    for (; t < T; t += 4) {
        int s0 = (t == 0) ? node : srcs[beg + t - 1];
        uint4 va = base[(size_t)s0 * 16 + l15];
        acc[0] += bflo(va.x); acc[1] += bfhi(va.x);
        acc[2] += bflo(va.y); acc[3] += bfhi(va.y);
        acc[4] += bflo(va.z); acc[5] += bfhi(va.z);
        acc[6] += bflo(va.w); acc[7] += bfhi(va.w);
    }
#pragma unroll
    for (int j = 0; j < 8; j++) {
        acc[j] += __shfl_xor(acc[j], 16);
        acc[j] += __shfl_xor(acc[j], 32);
    }
    if (g == 0) {
        const float dv = dinv[node];
        const float4* b4 = (const float4*)(bias + 8 * l15);
        float4 bb0 = b4[0], bb1 = b4[1];
        uint4 o;
        o.x = pack2(fmaxf(acc[0] * dv + bb0.x, 0.f), fmaxf(acc[1] * dv + bb0.y, 0.f));
        o.y = pack2(fmaxf(acc[2] * dv + bb0.z, 0.f), fmaxf(acc[3] * dv + bb0.w, 0.f));
        o.z = pack2(fmaxf(acc[4] * dv + bb1.x, 0.f), fmaxf(acc[5] * dv + bb1.y, 0.f));
        o.w = pack2(fmaxf(acc[6] * dv + bb1.z, 0.f), fmaxf(acc[7] * dv + bb1.w, 0.f));
        ((uint4*)outb)[(size_t)node * 16 + l15] = o;
    }
}

// ---------------- pull aggregation, F=64 bf16 rows (128B), 16B/lane, 8 rows/wave-load, fp32 out ----------------
__global__ __launch_bounds__(256) void k_agg64(const ushort* __restrict__ hws, const int* __restrict__ srcs,
                                               const int* __restrict__ offs, const float* __restrict__ dinv,
                                               const float* __restrict__ bias, float* __restrict__ out, int n) {
    const int wv = threadIdx.x >> 6, lane = threadIdx.x & 63;
    const int node = blockIdx.x * 4 + wv;
    if (node >= n) return;
    const int g = lane >> 3, l7 = lane & 7;
    const int beg = offs[node];
    const int T = offs[node + 1] - beg + 1;
    const uint4* base = (const uint4*)hws;  // row = 8 uint4
    float acc[8] = {};
    int t = g;
    for (; t + 8 < T; t += 16) {
        int s0 = (t == 0) ? node : srcs[beg + t - 1];
        int s1 = srcs[beg + t + 7];
        uint4 va = base[(size_t)s0 * 8 + l7];
        uint4 vb = base[(size_t)s1 * 8 + l7];
        acc[0] += bflo(va.x) + bflo(vb.x); acc[1] += bfhi(va.x) + bfhi(vb.x);
        acc[2] += bflo(va.y) + bflo(vb.y); acc[3] += bfhi(va.y) + bfhi(vb.y);
        acc[4] += bflo(va.z) + bflo(vb.z); acc[5] += bfhi(va.z) + bfhi(vb.z);
        acc[6] += bflo(va.w) + bflo(vb.w); acc[7] += bfhi(va.w) + bfhi(vb.w);
    }
    for (; t < T; t += 8) {
        int s0 = (t == 0) ? node : srcs[beg + t - 1];
        uint4 va = base[(size_t)s0 * 8 + l7];
        acc[0] += bflo(va.x); acc[1] += bfhi(va.x);
        acc[2] += bflo(va.y); acc[3] += bfhi(va.y);
        acc[4] += bflo(va.z); acc[5] += bfhi(va.z);
        acc[6] += bflo(va.w); acc[7] += bfhi(va.w);
    }
#pragma unroll
    for (int j = 0; j < 8; j++) {
        acc[j] += __shfl_xor(acc[j], 8);
        acc[j] += __shfl_xor(acc[j], 16);
        acc[j] += __shfl_xor(acc[j], 32);
    }
    if (g == 0) {
        const float dv = dinv[node];
        const float4* b4 = (const float4*)(bias + 8 * l7);
        float4 bb0 = b4[0], bb1 = b4[1];
        float4 o0, o1;
        o0.x = acc[0] * dv + bb0.x; o0.y = acc[1] * dv + bb0.y;
        o0.z = acc[2] * dv + bb0.z; o0.w = acc[3] * dv + bb0.w;
        o1.x = acc[4] * dv + bb1.x; o1.y = acc[5] * dv + bb1.y;
        o1.z = acc[6] * dv + bb1.z; o1.w = acc[7] * dv + bb1.w;
        ((float4*)out)[(size_t)node * 16 + 2 * l7] = o0;
        ((float4*)out)[(size_t)node * 16 + 2 * l7 + 1] = o1;
    }
}

static inline size_t align_up(size_t x, size_t a) { return (x + a - 1) & ~(a - 1); }

extern "C" void kernel_launch(void* const* d_in, const int* in_sizes, int n_in,
                              void* d_out, int out_size, void* d_ws, size_t ws_size,
                              hipStream_t stream) {
    const float* x = (const float*)d_in[0];
    const int* edges = (const int*)d_in[1];  // int32 per harness integer convention
    const float* W1 = (const float*)d_in[2];
    const float* b1 = (const float*)d_in[3];
    const float* W2 = (const float*)d_in[4];
    const float* b2 = (const float*)d_in[5];
    float* out = (float*)d_out;

    char* p = (char*)d_ws;
    int* count = (int*)p;      p += align_up(NN * 4, 256);
    int* incl = (int*)p;       p += align_up(NN * 4, 256);
    int* offsets = (int*)p;    p += align_up((NN + 1) * 4, 256);
    int* cursor = (int*)p;     p += align_up(NN * 4, 256);
    int* srcs = (int*)p;       p += align_up(NE * 4, 256);
    int* blocksum = (int*)p;   p += align_up(256 * 4, 256);
    float* dinv = (float*)p;   p += align_up(NN * 4, 256);
    ushort* w1t = (ushort*)p;  p += align_up(D_IN * D_HID * 2, 256);
    ushort* w2t = (ushort*)p;  p += align_up(D_HID * D_OUT * 2, 256);
    ushort* hw1s = (ushort*)p; p += align_up((size_t)NN * D_HID * 2, 256);
    ushort* hb = (ushort*)p;   p += align_up((size_t)NN * D_HID * 2, 256);
    ushort* hw2s = (ushort*)p; p += align_up((size_t)NN * D_OUT * 2, 256);

    const int nb_scan = (NN + SCAN_B - 1) / SCAN_B;  // 98

    hipMemsetAsync(count, 0, NN * 4, stream);
    k_count<<<(NE + 255) / 256, 256, 0, stream>>>(edges + NE, count, NE);
    k_scan1<<<nb_scan, SCAN_B, 0, stream>>>(count, incl, blocksum, NN);
    k_scan3<<<(NN + 255) / 256, 256, 0, stream>>>(incl, count, blocksum, nb_scan, offsets, cursor, dinv, NN);
    k_scatter<<<(NE + 255) / 256, 256, 0, stream>>>(edges, cursor, srcs, NE);
    k_castW<<<(D_IN * D_HID + D_HID * D_OUT + 255) / 256, 256, 0, stream>>>(W1, W2, w1t, w2t);

    const int g16_blocks = (NN + 63) / 64;  // 1563

    // layer 1: hw1s = (x @ W1) * dinv  (fp32 A, fused cast)
    k_gemm16<D_IN, D_HID, true><<<g16_blocks, 256, 0, stream>>>(x, w1t, dinv, hw1s, NN);
    k_agg128<<<(NN + 3) / 4, 256, 0, stream>>>(hw1s, srcs, offsets, dinv, b1, hb, NN);

    // layer 2: hw2s = (h @ W2) * dinv
    k_gemm16<D_HID, D_OUT, false><<<g16_blocks, 256, 0, stream>>>(hb, w2t, dinv, hw2s, NN);
    k_agg64<<<(NN + 3) / 4, 256, 0, stream>>>(hw2s, srcs, offsets, dinv, b2, out, NN);
}

// Round 7
// 368.853 us; speedup vs baseline: 1.1119x; 1.1119x over previous
//
#include <hip/hip_runtime.h>

typedef unsigned int uint;
typedef unsigned short ushort;
typedef __attribute__((ext_vector_type(8))) short bf16x8;
typedef __attribute__((ext_vector_type(4))) float f32x4;

#define NN 100000
#define NE 800000
#define D_IN 256
#define D_HID 128
#define D_OUT 64

// RNE fp32->bf16
__device__ __forceinline__ ushort f2bf(float f) {
    uint u = __float_as_uint(f);
    return (ushort)((u + 0x7fffu + ((u >> 16) & 1u)) >> 16);
}
__device__ __forceinline__ float bflo(uint u) { return __uint_as_float(u << 16); }
__device__ __forceinline__ float bfhi(uint u) { return __uint_as_float(u & 0xffff0000u); }
__device__ __forceinline__ uint pack2(float lo, float hi) {
    return (uint)f2bf(lo) | ((uint)f2bf(hi) << 16);
}
__device__ __forceinline__ bf16x8 pack8(float4 a, float4 b) {
    bf16x8 r;
    r[0] = (short)f2bf(a.x); r[1] = (short)f2bf(a.y); r[2] = (short)f2bf(a.z); r[3] = (short)f2bf(a.w);
    r[4] = (short)f2bf(b.x); r[5] = (short)f2bf(b.y); r[6] = (short)f2bf(b.z); r[7] = (short)f2bf(b.w);
    return r;
}

// ---------------- degree count ----------------
__global__ __launch_bounds__(256) void k_count(const int* __restrict__ dst, int* __restrict__ count, int e) {
    int i = blockIdx.x * 256 + threadIdx.x;
    if (i < e) {
        unsigned d = (unsigned)dst[i];
        if (d < NN) atomicAdd(&count[d], 1);
    }
}

// ---------------- scan stage 1 ----------------
#define SCAN_B 1024
__global__ __launch_bounds__(SCAN_B) void k_scan1(const int* __restrict__ count, int* __restrict__ incl,
                                                  int* __restrict__ blocksum, int n) {
    __shared__ int tmp[SCAN_B];
    int t = threadIdx.x;
    int gid = blockIdx.x * SCAN_B + t;
    int v = (gid < n) ? count[gid] : 0;
    tmp[t] = v;
    __syncthreads();
    for (int off = 1; off < SCAN_B; off <<= 1) {
        int u = (t >= off) ? tmp[t - off] : 0;
        __syncthreads();
        tmp[t] += u;
        __syncthreads();
    }
    if (gid < n) incl[gid] = tmp[t];
    if (t == SCAN_B - 1) blocksum[blockIdx.x] = tmp[t];
}

// ---------------- scan stage 2 (merged): finalize offsets/cursor/dinv ----------------
__global__ __launch_bounds__(256) void k_scan3(const int* __restrict__ incl, const int* __restrict__ count,
                                               const int* __restrict__ blocksum, int nb, int* __restrict__ offsets,
                                               int* __restrict__ cursor, float* __restrict__ dinv, int n) {
    __shared__ int bs[128];
    int t = threadIdx.x;
    if (t < 128) bs[t] = (t < nb) ? blocksum[t] : 0;
    __syncthreads();
    int i = blockIdx.x * 256 + t;
    if (i < n) {
        int b = i >> 10;
        int off = 0;
        for (int j = 0; j < b; j++) off += bs[j];
        int inc = incl[i] + off;
        int exc = inc - count[i];
        offsets[i] = exc;
        cursor[i] = exc;
        dinv[i] = rsqrtf((float)(count[i] + 1));  // +1 self-loop
        if (i == n - 1) offsets[n] = inc;
    }
}

// ---------------- scatter edges into CSC order ----------------
__global__ __launch_bounds__(256) void k_scatter(const int* __restrict__ edges, int* __restrict__ cursor,
                                                 int* __restrict__ srcs, int e) {
    int i = blockIdx.x * 256 + threadIdx.x;
    if (i < e) {
        unsigned s = (unsigned)edges[i];
        unsigned d = (unsigned)edges[e + i];
        if (s < NN && d < NN) {
            int pos = atomicAdd(&cursor[d], 1);
            srcs[pos] = (int)s;
        }
    }
}

// ---------------- both weights: W[K][N] fp32 -> WT[N][K] bf16 ----------------
__global__ __launch_bounds__(256) void k_castW(const float* __restrict__ W1, const float* __restrict__ W2,
                                               ushort* __restrict__ w1t, ushort* __restrict__ w2t) {
    int t = blockIdx.x * 256 + threadIdx.x;
    if (t < D_IN * D_HID) {
        int n = t / D_IN, k = t % D_IN;
        w1t[t] = f2bf(W1[(size_t)k * D_HID + n]);
    } else {
        int u = t - D_IN * D_HID;
        if (u < D_HID * D_OUT) {
            int n = u / D_HID, k = u % D_HID;
            w2t[u] = f2bf(W2[(size_t)k * D_OUT + n]);
        }
    }
}

// ---------------- MFMA GEMM with B staged in LDS (fragment-permuted, conflict-free) ----------------
// C[M,N] = (A[M,K] @ B[K,N]) * dinv[row], bf16 out. BT = B^T [N][K] bf16.
// Block = 256 thr (4 waves), 128 rows/block, 32 rows/wave. B lives in LDS:
// chunk c (16B) at lds_u4[c], c = (nf*KK+kk)*64 + l15*4 + g  -> lane-contiguous reads.
template <int K_DIM, int N_DIM, bool AF32>
__global__ __launch_bounds__(256) void k_gemm_lds(const void* __restrict__ Av, const ushort* __restrict__ BT,
                                                  const float* __restrict__ dinv, ushort* __restrict__ C, int M) {
    constexpr int NF = N_DIM / 16;
    constexpr int KK = K_DIM / 32;
    constexpr int CHUNKS = N_DIM * K_DIM / 8;  // 16B units
    __shared__ ushort lds[N_DIM * K_DIM];

    const int tid = threadIdx.x;
    const int w = tid >> 6, lane = tid & 63;
    const int l15 = lane & 15, g = lane >> 4;  // g in 0..3

    // stage BT -> LDS in permuted layout (one time; B is L2/L3-hot)
    {
        const uint4* src = (const uint4*)BT;
        uint4* dstl = (uint4*)lds;
#pragma unroll
        for (int c = tid; c < CHUNKS; c += 256) {
            int nfkk = c >> 6, l15g = c & 63;
            int sl15 = l15g >> 2, sg = l15g & 3;
            int nf = nfkk / KK, kk = nfkk % KK;
            int r = nf * 16 + sl15;
            int kc = kk * 32 + sg * 8;
            dstl[c] = src[(r * K_DIM + kc) >> 3];
        }
    }
    __syncthreads();

    const int row0 = blockIdx.x * 128 + w * 32;
    const int rA0 = min(row0 + l15, M - 1);
    const int rA1 = min(row0 + 16 + l15, M - 1);

    f32x4 acc[2][NF];
#pragma unroll
    for (int mf = 0; mf < 2; mf++)
#pragma unroll
        for (int nf = 0; nf < NF; nf++) acc[mf][nf] = (f32x4){0.f, 0.f, 0.f, 0.f};

    const uint4* pb = ((const uint4*)lds) + l15 * 4 + g;  // + (nf*KK+kk)*64 immediate

#pragma unroll
    for (int kk = 0; kk < KK; ++kk) {
        bf16x8 a0, a1;
        if constexpr (AF32) {
            const float* A = (const float*)Av;
            const float4* p0 = (const float4*)(A + (size_t)rA0 * K_DIM + g * 8 + kk * 32);
            const float4* p1 = (const float4*)(A + (size_t)rA1 * K_DIM + g * 8 + kk * 32);
            float4 v00 = p0[0], v01 = p0[1], v10 = p1[0], v11 = p1[1];
            a0 = pack8(v00, v01);
            a1 = pack8(v10, v11);
        } else {
            const ushort* A = (const ushort*)Av;
            a0 = *reinterpret_cast<const bf16x8*>(A + (size_t)rA0 * K_DIM + g * 8 + kk * 32);
            a1 = *reinterpret_cast<const bf16x8*>(A + (size_t)rA1 * K_DIM + g * 8 + kk * 32);
        }
#pragma unroll
        for (int nf = 0; nf < NF; nf++) {
            bf16x8 b = *reinterpret_cast<const bf16x8*>(pb + (nf * KK + kk) * 64);
            acc[0][nf] = __builtin_amdgcn_mfma_f32_16x16x32_bf16(a0, b, acc[0][nf], 0, 0, 0);
            acc[1][nf] = __builtin_amdgcn_mfma_f32_16x16x32_bf16(a1, b, acc[1][nf], 0, 0, 0);
        }
    }

    // D layout: row_in_tile = g*4 + r, col = l15  [learn_hip m89/m91]
#pragma unroll
    for (int mf = 0; mf < 2; mf++) {
#pragma unroll
        for (int r = 0; r < 4; r++) {
            int rr = row0 + mf * 16 + g * 4 + r;
            if (rr < M) {
                float dv = dinv[rr];
#pragma unroll
                for (int nf = 0; nf < NF; nf++)
                    C[(size_t)rr * N_DIM + nf * 16 + l15] = f2bf(acc[mf][nf][r] * dv);
            }
        }
    }
}

// ---------------- pull aggregation, F=128 bf16 rows (256B), 16B/lane, 4 rows/wave-load ----------------
__global__ __launch_bounds__(256) void k_agg128(const ushort* __restrict__ hws, const int* __restrict__ srcs,
                                                const int* __restrict__ offs, const float* __restrict__ dinv,
                                                const float* __restrict__ bias, ushort* __restrict__ outb, int n) {
    const int wv = threadIdx.x >> 6, lane = threadIdx.x & 63;
    const int node = blockIdx.x * 4 + wv;
    if (node >= n) return;
    const int g = lane >> 4, l15 = lane & 15;
    const int beg = offs[node];
    const int T = offs[node + 1] - beg + 1;  // items: 0 = self, t>=1 -> srcs[beg+t-1]
    const uint4* base = (const uint4*)hws;   // row = 16 uint4
    float acc[8] = {};
    int t = g;
    for (; t + 4 < T; t += 8) {
        int s0 = (t == 0) ? node : srcs[beg + t - 1];
        int s1 = srcs[beg + t + 3];
        uint4 va = base[(size_t)s0 * 16 + l15];
        uint4 vb = base[(size_t)s1 * 16 + l15];
        acc[0] += bflo(va.x) + bflo(vb.x); acc[1] += bfhi(va.x) + bfhi(vb.x);
        acc[2] += bflo(va.y) + bflo(vb.y); acc[3] += bfhi(va.y) + bfhi(vb.y);
        acc[4] += bflo(va.z) + bflo(vb.z); acc[5] += bfhi(va.z) + bfhi(vb.z);
        acc[6] += bflo(va.w) + bflo(vb.w); acc[7] += bfhi(va.w) + bfhi(vb.w);
    }
    for (; t < T; t += 4) {
        int s0 = (t == 0) ? node : srcs[beg + t - 1];
        uint4 va = base[(size_t)s0 * 16 + l15];
        acc[0] += bflo(va.x); acc[1] += bfhi(va.x);
        acc[2] += bflo(va.y); acc[3] += bfhi(va.y);
        acc[4] += bflo(va.z); acc[5] += bfhi(va.z);
        acc[6] += bflo(va.w); acc[7] += bfhi(va.w);
    }
#pragma unroll
    for (int j = 0; j < 8; j++) {
        acc[j] += __shfl_xor(acc[j], 16);
        acc[j] += __shfl_xor(acc[j], 32);
    }
    if (g == 0) {
        const float dv = dinv[node];
        const float4* b4 = (const float4*)(bias + 8 * l15);
        float4 bb0 = b4[0], bb1 = b4[1];
        uint4 o;
        o.x = pack2(fmaxf(acc[0] * dv + bb0.x, 0.f), fmaxf(acc[1] * dv + bb0.y, 0.f));
        o.y = pack2(fmaxf(acc[2] * dv + bb0.z, 0.f), fmaxf(acc[3] * dv + bb0.w, 0.f));
        o.z = pack2(fmaxf(acc[4] * dv + bb1.x, 0.f), fmaxf(acc[5] * dv + bb1.y, 0.f));
        o.w = pack2(fmaxf(acc[6] * dv + bb1.z, 0.f), fmaxf(acc[7] * dv + bb1.w, 0.f));
        ((uint4*)outb)[(size_t)node * 16 + l15] = o;
    }
}

// ---------------- pull aggregation, F=64 bf16 rows (128B), 16B/lane, fp32 out ----------------
__global__ __launch_bounds__(256) void k_agg64(const ushort* __restrict__ hws, const int* __restrict__ srcs,
                                               const int* __restrict__ offs, const float* __restrict__ dinv,
                                               const float* __restrict__ bias, float* __restrict__ out, int n) {
    const int wv = threadIdx.x >> 6, lane = threadIdx.x & 63;
    const int node = blockIdx.x * 4 + wv;
    if (node >= n) return;
    const int g = lane >> 3, l7 = lane & 7;
    const int beg = offs[node];
    const int T = offs[node + 1] - beg + 1;
    const uint4* base = (const uint4*)hws;  // row = 8 uint4
    float acc[8] = {};
    int t = g;
    for (; t + 8 < T; t += 16) {
        int s0 = (t == 0) ? node : srcs[beg + t - 1];
        int s1 = srcs[beg + t + 7];
        uint4 va = base[(size_t)s0 * 8 + l7];
        uint4 vb = base[(size_t)s1 * 8 + l7];
        acc[0] += bflo(va.x) + bflo(vb.x); acc[1] += bfhi(va.x) + bfhi(vb.x);
        acc[2] += bflo(va.y) + bflo(vb.y); acc[3] += bfhi(va.y) + bfhi(vb.y);
        acc[4] += bflo(va.z) + bflo(vb.z); acc[5] += bfhi(va.z) + bfhi(vb.z);
        acc[6] += bflo(va.w) + bflo(vb.w); acc[7] += bfhi(va.w) + bfhi(vb.w);
    }
    for (; t < T; t += 8) {
        int s0 = (t == 0) ? node : srcs[beg + t - 1];
        uint4 va = base[(size_t)s0 * 8 + l7];
        acc[0] += bflo(va.x); acc[1] += bfhi(va.x);
        acc[2] += bflo(va.y); acc[3] += bfhi(va.y);
        acc[4] += bflo(va.z); acc[5] += bfhi(va.z);
        acc[6] += bflo(va.w); acc[7] += bfhi(va.w);
    }
#pragma unroll
    for (int j = 0; j < 8; j++) {
        acc[j] += __shfl_xor(acc[j], 8);
        acc[j] += __shfl_xor(acc[j], 16);
        acc[j] += __shfl_xor(acc[j], 32);
    }
    if (g == 0) {
        const float dv = dinv[node];
        const float4* b4 = (const float4*)(bias + 8 * l7);
        float4 bb0 = b4[0], bb1 = b4[1];
        float4 o0, o1;
        o0.x = acc[0] * dv + bb0.x; o0.y = acc[1] * dv + bb0.y;
        o0.z = acc[2] * dv + bb0.z; o0.w = acc[3] * dv + bb0.w;
        o1.x = acc[4] * dv + bb1.x; o1.y = acc[5] * dv + bb1.y;
        o1.z = acc[6] * dv + bb1.z; o1.w = acc[7] * dv + bb1.w;
        ((float4*)out)[(size_t)node * 16 + 2 * l7] = o0;
        ((float4*)out)[(size_t)node * 16 + 2 * l7 + 1] = o1;
    }
}

static inline size_t align_up(size_t x, size_t a) { return (x + a - 1) & ~(a - 1); }

extern "C" void kernel_launch(void* const* d_in, const int* in_sizes, int n_in,
                              void* d_out, int out_size, void* d_ws, size_t ws_size,
                              hipStream_t stream) {
    const float* x = (const float*)d_in[0];
    const int* edges = (const int*)d_in[1];  // int32 per harness integer convention
    const float* W1 = (const float*)d_in[2];
    const float* b1 = (const float*)d_in[3];
    const float* W2 = (const float*)d_in[4];
    const float* b2 = (const float*)d_in[5];
    float* out = (float*)d_out;

    char* p = (char*)d_ws;
    int* count = (int*)p;      p += align_up(NN * 4, 256);
    int* incl = (int*)p;       p += align_up(NN * 4, 256);
    int* offsets = (int*)p;    p += align_up((NN + 1) * 4, 256);
    int* cursor = (int*)p;     p += align_up(NN * 4, 256);
    int* srcs = (int*)p;       p += align_up(NE * 4, 256);
    int* blocksum = (int*)p;   p += align_up(256 * 4, 256);
    float* dinv = (float*)p;   p += align_up(NN * 4, 256);
    ushort* w1t = (ushort*)p;  p += align_up(D_IN * D_HID * 2, 256);
    ushort* w2t = (ushort*)p;  p += align_up(D_HID * D_OUT * 2, 256);
    ushort* hw1s = (ushort*)p; p += align_up((size_t)NN * D_HID * 2, 256);
    ushort* hb = (ushort*)p;   p += align_up((size_t)NN * D_HID * 2, 256);
    ushort* hw2s = (ushort*)p; p += align_up((size_t)NN * D_OUT * 2, 256);

    const int nb_scan = (NN + SCAN_B - 1) / SCAN_B;  // 98

    hipMemsetAsync(count, 0, NN * 4, stream);
    k_count<<<(NE + 255) / 256, 256, 0, stream>>>(edges + NE, count, NE);
    k_scan1<<<nb_scan, SCAN_B, 0, stream>>>(count, incl, blocksum, NN);
    k_scan3<<<(NN + 255) / 256, 256, 0, stream>>>(incl, count, blocksum, nb_scan, offsets, cursor, dinv, NN);
    k_scatter<<<(NE + 255) / 256, 256, 0, stream>>>(edges, cursor, srcs, NE);
    k_castW<<<(D_IN * D_HID + D_HID * D_OUT + 255) / 256, 256, 0, stream>>>(W1, W2, w1t, w2t);

    const int gemm_blocks = (NN + 127) / 128;  // 782

    // layer 1: hw1s = (x @ W1) * dinv  (fp32 A, fused cast; B in LDS)
    k_gemm_lds<D_IN, D_HID, true><<<gemm_blocks, 256, 0, stream>>>(x, w1t, dinv, hw1s, NN);
    k_agg128<<<(NN + 3) / 4, 256, 0, stream>>>(hw1s, srcs, offsets, dinv, b1, hb, NN);

    // layer 2: hw2s = (h @ W2) * dinv
    k_gemm_lds<D_HID, D_OUT, false><<<gemm_blocks, 256, 0, stream>>>(hb, w2t, dinv, hw2s, NN);
    k_agg64<<<(NN + 3) / 4, 256, 0, stream>>>(hw2s, srcs, offsets, dinv, b2, out, NN);
}